// Round 11
// baseline (776.205 us; speedup 1.0000x reference)
//
#include <hip/hip_runtime.h>
#include <hip/hip_bf16.h>
#include <stdint.h>

// DIAGNOSTIC ROUND. Same algorithm as r4 (champion, 187us), but:
//  - k_convert_probe: plain-load convert repeated x4 IN ONE DISPATCH
//  - k_gemm_probe:    pass-1 gemm repeated x16 IN ONE DISPATCH
// so both exceed the ~155us harness poison-fills and surface in the top-5
// rocprof table with full counters. Outputs are identical to REP=1 (acc
// re-zeroed per rep; same stores), so correctness/determinism unchanged.
// dur_us is intentionally sacrificed this round.

typedef __attribute__((ext_vector_type(8))) short     bf16x8;
typedef __attribute__((ext_vector_type(8))) uint16_t  u16x8;
typedef __attribute__((ext_vector_type(4))) float     f32x4;

#define NN 8192
#define NF 128
#define ZSTRIDE (8192 + 64)

#define WAITV(n) asm volatile("s_waitcnt vmcnt(" #n ")" ::: "memory")
#define WAITL0   asm volatile("s_waitcnt lgkmcnt(0)" ::: "memory")

__device__ inline uint16_t f2bf(float f) {
    uint32_t u = __builtin_bit_cast(uint32_t, f);
    u += 0x7fffu + ((u >> 16) & 1u);     // round-to-nearest-even
    return (uint16_t)(u >> 16);
}

__device__ inline void gl2lds16(const void* g, uint8_t* l) {
    __builtin_amdgcn_global_load_lds(
        (const __attribute__((address_space(1))) uint32_t*)g,
        (__attribute__((address_space(3))) uint32_t*)l,
        16, 0, 0);
}

__device__ inline bf16x8 ld16(const uint8_t* p) {
    return __builtin_bit_cast(bf16x8, *(const u16x8*)p);
}

// ---- convert probe: plain f32x4 loads, REP reps in one dispatch ------------
__global__ __launch_bounds__(256) void k_convert_probe(
    const float* __restrict__ S, uint16_t* __restrict__ S16) {
    const size_t base = (size_t)blockIdx.x * 256 + threadIdx.x;
    const size_t stride = (size_t)gridDim.x * 256;
#pragma unroll 1
    for (int rep = 0; rep < 4; ++rep) {
#pragma unroll 4
        for (int it = 0; it < 16; ++it) {
            size_t i = base + (size_t)it * stride;
            f32x4 a = *(const f32x4*)(S + i * 8);
            f32x4 b = *(const f32x4*)(S + i * 8 + 4);
            u16x8 p;
#pragma unroll
            for (int j = 0; j < 4; ++j) { p[j] = f2bf(a[j]); p[j + 4] = f2bf(b[j]); }
            *(u16x8*)(S16 + i * 8) = p;
        }
    }
}

// ---- y = h0*X ; ZT0 = X^T bf16 --------------------------------------------
__global__ __launch_bounds__(256) void k_prep(const float* __restrict__ X,
                                              const float* __restrict__ coeff,
                                              float* __restrict__ y,
                                              uint16_t* __restrict__ ZT0) {
    __shared__ float tile[16][NF + 4];
    const int t  = threadIdx.x;
    const int r0 = blockIdx.x * 16;
    const float h0 = coeff[0];
#pragma unroll
    for (int i = 0; i < 2; ++i) {
        int o   = (i * 256 + t) * 4;
        int row = o >> 7, col = o & 127;
        f32x4 v = *(const f32x4*)(X + (size_t)(r0 + row) * NF + col);
        *(f32x4*)&tile[row][col] = v;
        *(f32x4*)(y + (size_t)(r0 + row) * NF + col) = v * h0;
    }
    __syncthreads();
    const int c = t >> 1, rh = t & 1;
    u16x8 pk;
#pragma unroll
    for (int e = 0; e < 8; ++e) pk[e] = f2bf(tile[rh * 8 + e][c]);
    *(u16x8*)(ZT0 + (size_t)c * ZSTRIDE + r0 + rh * 8) = pk;
}

// ---- shared gemm body: r4's 3-buffer depth-2 counted-vmcnt core ------------
template<int KS, int REP>
__device__ inline void gemm_body(const uint16_t* __restrict__ S16,
                                 const uint16_t* __restrict__ ZTin,
                                 float* __restrict__ P,
                                 uint8_t* smem, int bx, int t) {
    const int lane = t & 63, w = t >> 6, m = lane & 15, g = lane >> 4;
    const int rt = w & 3, ch = w >> 2;
    const int mt = bx & 127, ks = bx >> 7;
    const int r0 = mt * 64;
    const int kb = ks * (NN / KS);
    constexpr int NT = (NN / KS) / 64;
    static_assert(NT >= 3, "pipeline needs >=3 k-tiles");

    const int srow = t >> 3, sc = t & 7;
    const int scs  = (sc ^ (srow & 7)) << 3;
    const uint16_t* asrc = S16  + (size_t)(r0 + srow) * NN + kb + scs;
    const uint16_t* bsrc = ZTin + (size_t)srow * ZSTRIDE   + kb + scs;

    const int sw   = m & 7;
    const int aoff = (rt * 16 + m) * 128 + ((g ^ sw) << 4);
    const int bof  = 8192 + (ch * 64 + m) * 128 + ((g ^ sw) << 4);

    auto stage = [&](int buf, int kt) {
        const int ko = kt * 64;
        uint8_t* b = smem + buf * 24576;
        gl2lds16(asrc + ko, b + t * 16);
        gl2lds16(bsrc + ko, b + 8192 + t * 16);
        gl2lds16(bsrc + (size_t)64 * ZSTRIDE + ko, b + 16384 + t * 16);
    };

#pragma unroll 1
    for (int rep = 0; rep < REP; ++rep) {
        f32x4 acc[4] = {};
        stage(0, 0);
        stage(1, 1);
        int cur = 0;
#pragma unroll 1
        for (int kt = 0; kt < NT; ++kt) {
            if (kt + 2 < NT) {
                int nxt = cur + 2; if (nxt >= 3) nxt -= 3;
                stage(nxt, kt + 2);
                WAITV(6);             // stage(kt) done; (kt+1),(kt+2) in flight
            } else if (kt + 2 == NT) {
                WAITV(3);
            } else {
                WAITV(0);
            }
            __builtin_amdgcn_s_barrier();
            __builtin_amdgcn_sched_barrier(0);
            const uint8_t* bb = smem + cur * 24576;
            bf16x8 a0 = ld16(bb + aoff);
            bf16x8 a1 = ld16(bb + (aoff ^ 64));
#pragma unroll
            for (int ct = 0; ct < 4; ++ct) {
                acc[ct] = __builtin_amdgcn_mfma_f32_16x16x32_bf16(
                    a0, ld16(bb + bof + ct * 16 * 128), acc[ct], 0, 0, 0);
                acc[ct] = __builtin_amdgcn_mfma_f32_16x16x32_bf16(
                    a1, ld16(bb + ((bof + ct * 16 * 128) ^ 64)), acc[ct], 0, 0, 0);
            }
            WAITL0;
            __builtin_amdgcn_sched_barrier(0);
            __builtin_amdgcn_s_barrier();
            cur = (cur + 1 == 3) ? 0 : cur + 1;
        }

        float* pb = P + ((size_t)ks * NN + r0 + rt * 16 + 4 * g) * NF + ch * 64 + m;
#pragma unroll
        for (int ct = 0; ct < 4; ++ct)
#pragma unroll
            for (int i = 0; i < 4; ++i)
                pb[(size_t)i * NF + ct * 16] = acc[ct][i];

        if (REP > 1) {                // drain P stores so vmcnt counts stay exact
            WAITV(0);
            __builtin_amdgcn_s_barrier();
        }
    }
}

// probe: pass-1 gemm x16 in one dispatch (distinct name for the profile)
__global__ __launch_bounds__(512, 4) void k_gemm_probe(
    const uint16_t* __restrict__ S16, const uint16_t* __restrict__ ZTin,
    float* __restrict__ P)
{
    __shared__ __align__(16) uint8_t smem[3][24576];
    gemm_body<4, 16>(S16, ZTin, P, &smem[0][0], blockIdx.x, threadIdx.x);
}

template<int KS>
__global__ __launch_bounds__(512, 4) void k_gemm_bf(
    const uint16_t* __restrict__ S16, const uint16_t* __restrict__ ZTin,
    float* __restrict__ P)
{
    __shared__ __align__(16) uint8_t smem[3][24576];
    gemm_body<KS, 1>(S16, ZTin, P, &smem[0][0], blockIdx.x, threadIdx.x);
}

// ---- combine: Z = sum_ks P ; y += h*Z ; ZT' = bf16(Z^T) --------------------
template<int KS, bool WRITE_ZT>
__global__ __launch_bounds__(256) void k_combine(const float* __restrict__ P,
                                                 float* __restrict__ y,
                                                 uint16_t* __restrict__ ZTout,
                                                 const float* __restrict__ coeff,
                                                 int pass) {
    __shared__ float tile[16][NF + 4];
    const int t = threadIdx.x, r0 = blockIdx.x * 16;
    const float hk = coeff[pass];
    const int row = t >> 4, col = (t & 15) * 8;
    const size_t off = (size_t)(r0 + row) * NF + col;
    f32x4 s0 = *(const f32x4*)(P + off);
    f32x4 s1 = *(const f32x4*)(P + off + 4);
#pragma unroll
    for (int k = 1; k < KS; ++k) {
        s0 += *(const f32x4*)(P + (size_t)k * NN * NF + off);
        s1 += *(const f32x4*)(P + (size_t)k * NN * NF + off + 4);
    }
    float* yp = y + off;
    f32x4 y0 = *(const f32x4*)yp, y1 = *(const f32x4*)(yp + 4);
    *(f32x4*)yp       = y0 + hk * s0;
    *(f32x4*)(yp + 4) = y1 + hk * s1;
    if (WRITE_ZT) {
        *(f32x4*)&tile[row][col]     = s0;
        *(f32x4*)&tile[row][col + 4] = s1;
        __syncthreads();
        const int c = t >> 1, rh = t & 1;
        u16x8 pk;
#pragma unroll
        for (int e = 0; e < 8; ++e) pk[e] = f2bf(tile[rh * 8 + e][c]);
        *(u16x8*)(ZTout + (size_t)c * ZSTRIDE + r0 + rh * 8) = pk;
    }
}

template<int KS>
static void run(const float* X, const float* S, const float* coeff, float* y,
                uint16_t* ZT0, uint16_t* ZT1, uint16_t* S16, float* P,
                bool probe, hipStream_t stream) {
    k_prep<<<dim3(512), dim3(256), 0, stream>>>(X, coeff, y, ZT0);
    k_convert_probe<<<dim3(2048), dim3(256), 0, stream>>>(S, S16);
    if (probe && KS == 4)
        k_gemm_probe<<<dim3(512), dim3(512), 0, stream>>>(S16, ZT0, P);
    else
        k_gemm_bf<KS><<<dim3(128 * KS), dim3(512), 0, stream>>>(S16, ZT0, P);
    k_combine<KS, true ><<<dim3(512), dim3(256), 0, stream>>>(P, y, ZT1, coeff, 1);
    k_gemm_bf<KS><<<dim3(128 * KS), dim3(512), 0, stream>>>(S16, ZT1, P);
    k_combine<KS, true ><<<dim3(512), dim3(256), 0, stream>>>(P, y, ZT0, coeff, 2);
    k_gemm_bf<KS><<<dim3(128 * KS), dim3(512), 0, stream>>>(S16, ZT0, P);
    k_combine<KS, false><<<dim3(512), dim3(256), 0, stream>>>(P, y, nullptr, coeff, 3);
}

extern "C" void kernel_launch(void* const* d_in, const int* in_sizes, int n_in,
                              void* d_out, int out_size, void* d_ws, size_t ws_size,
                              hipStream_t stream) {
    const float* X     = (const float*)d_in[0];
    const float* S     = (const float*)d_in[1];
    const float* coeff = (const float*)d_in[2];
    float* y = (float*)d_out;

    uint8_t* ws = (uint8_t*)d_ws;
    const size_t zb     = ((size_t)NF * ZSTRIDE * sizeof(uint16_t) + 255) & ~(size_t)255;
    const size_t s16b   = (size_t)NN * NN * sizeof(uint16_t);
    const size_t base   = 2 * zb + s16b;
    const size_t pslice = (size_t)NN * NF * sizeof(float);
    uint16_t* ZT0 = (uint16_t*)ws;
    uint16_t* ZT1 = (uint16_t*)(ws + zb);
    uint16_t* S16 = (uint16_t*)(ws + 2 * zb);
    float*    P   = (float*)(ws + base);

    if (ws_size >= base + 4 * pslice)
        run<4>(X, S, coeff, y, ZT0, ZT1, S16, P, true, stream);
    else if (ws_size >= base + 2 * pslice)
        run<2>(X, S, coeff, y, ZT0, ZT1, S16, P, false, stream);
    else
        run<1>(X, S, coeff, y, ZT0, ZT1, S16, P, false, stream);
}

// Round 12
// 212.666 us; speedup vs baseline: 3.6499x; 3.6499x over previous
//
#include <hip/hip_runtime.h>
#include <hip/hip_bf16.h>
#include <stdint.h>

// y = sum_{k=0}^{3} h_k * S^k X,  X [8192,128] f32, S [8192,8192] f32.
// r11 probe: gemm pass = 28.7us at 3.2 TB/s -- A staged as 128B granules at
// 16KB stride (DRAM-hostile). Fix: S16 stored TILE-LINEAR: per (mt,ks) tile
// (64 rows x 2048 k), data laid out as 32 contiguous 8KB k-tile chunks in
// exactly stage order, so each gemm stage fetches one contiguous 8KB block.
//   k_prep:      y = h0*X ; ZT0 = X^T bf16
//   k_convert_t: S f32 -> S16T tiled bf16 (LDS-transposed; reads 1KB bursts,
//                writes 32KB linear)
//   3x: k_gemm_bf<KS=4,tiled> (3-buffer depth-2 counted-vmcnt, XOR-swizzled
//       LDS, grid 512) -> P  + k_combine<4>

typedef __attribute__((ext_vector_type(8))) short     bf16x8;
typedef __attribute__((ext_vector_type(8))) uint16_t  u16x8;
typedef __attribute__((ext_vector_type(4))) float     f32x4;

#define NN 8192
#define NF 128
#define ZSTRIDE (8192 + 64)

#define WAITV(n) asm volatile("s_waitcnt vmcnt(" #n ")" ::: "memory")
#define WAITL0   asm volatile("s_waitcnt lgkmcnt(0)" ::: "memory")

__device__ inline uint16_t f2bf(float f) {
    uint32_t u = __builtin_bit_cast(uint32_t, f);
    u += 0x7fffu + ((u >> 16) & 1u);     // round-to-nearest-even
    return (uint16_t)(u >> 16);
}

__device__ inline void gl2lds16(const void* g, uint8_t* l) {
    __builtin_amdgcn_global_load_lds(
        (const __attribute__((address_space(1))) uint32_t*)g,
        (__attribute__((address_space(3))) uint32_t*)l,
        16, 0, 0);
}

__device__ inline bf16x8 ld16(const uint8_t* p) {
    return __builtin_bit_cast(bf16x8, *(const u16x8*)p);
}

// ---- y = h0*X ; ZT0 = X^T bf16 --------------------------------------------
__global__ __launch_bounds__(256) void k_prep(const float* __restrict__ X,
                                              const float* __restrict__ coeff,
                                              float* __restrict__ y,
                                              uint16_t* __restrict__ ZT0) {
    __shared__ float tile[16][NF + 4];
    const int t  = threadIdx.x;
    const int r0 = blockIdx.x * 16;
    const float h0 = coeff[0];
#pragma unroll
    for (int i = 0; i < 2; ++i) {
        int o   = (i * 256 + t) * 4;
        int row = o >> 7, col = o & 127;
        f32x4 v = *(const f32x4*)(X + (size_t)(r0 + row) * NF + col);
        *(f32x4*)&tile[row][col] = v;
        *(f32x4*)(y + (size_t)(r0 + row) * NF + col) = v * h0;
    }
    __syncthreads();
    const int c = t >> 1, rh = t & 1;
    u16x8 pk;
#pragma unroll
    for (int e = 0; e < 8; ++e) pk[e] = f2bf(tile[rh * 8 + e][c]);
    *(u16x8*)(ZT0 + (size_t)c * ZSTRIDE + r0 + rh * 8) = pk;
}

// ---- convert S -> tiled S16T ----------------------------------------------
// block bx: mt = bx&127, ks = bx>>7. Tile = rows [mt*64,..+64) x k [ks*2048..).
// Tiled layout: tile_base = (mt*4+ks)*131072; elem (rr, kt*64+kk) at
// tile_base + kt*4096 + rr*64 + kk. Per 256-k chunk: read 64x1KB row bursts,
// LDS-transpose (32KB), write one 32KB linear block.
__global__ __launch_bounds__(256) void k_convert_t(const float* __restrict__ S,
                                                   uint16_t* __restrict__ S16T) {
    __shared__ __align__(16) uint16_t lds[16384];   // 32 KB
    const int t = threadIdx.x, bx = blockIdx.x;
    const int mt = bx & 127, ks = bx >> 7;
    const int r0 = mt * 64, kb = ks * 2048;
    uint16_t* tb = S16T + (size_t)(mt * 4 + ks) * 131072;

#pragma unroll 1
    for (int kc = 0; kc < 8; ++kc) {
#pragma unroll
        for (int si = 0; si < 8; ++si) {
            int id = si * 256 + t;            // 0..2047
            int rr = id >> 5, c8 = id & 31;
            const float* src = S + (size_t)(r0 + rr) * NN + kb + kc * 256 + c8 * 8;
            f32x4 a = *(const f32x4*)src;
            f32x4 b = *(const f32x4*)(src + 4);
            u16x8 p;
#pragma unroll
            for (int j = 0; j < 4; ++j) { p[j] = f2bf(a[j]); p[j + 4] = f2bf(b[j]); }
            // lds elem = ktl*4096 + rr*64 + (c8&7)*8
            *(u16x8*)&lds[((c8 >> 3) * 64 + rr) * 64 + (c8 & 7) * 8] = p;
        }
        __syncthreads();
        uint16_t* dst = tb + kc * 16384;
#pragma unroll
        for (int si = 0; si < 8; ++si) {
            int id = si * 256 + t;
            *(u16x8*)(dst + id * 8) = *(const u16x8*)&lds[id * 8];
        }
        __syncthreads();
    }
}

// ---- GEMM: tiled A staging, 3-buffer depth-2 counted-vmcnt -----------------
// KS=4 fixed for tiled layout. grid 512: mt = bx&127, ks = bx>>7.
__global__ __launch_bounds__(512, 4) void k_gemm_bf(
    const uint16_t* __restrict__ S16T, const uint16_t* __restrict__ ZTin,
    float* __restrict__ P)
{
    __shared__ __align__(16) uint8_t smem[3][24576];   // A 8KB | B 16KB
    const int t = threadIdx.x, lane = t & 63;
    const int w = t >> 6, m = lane & 15, g = lane >> 4;
    const int rt = w & 3, ch = w >> 2;
    const int mt = blockIdx.x & 127, ks = blockIdx.x >> 7;
    const int r0 = mt * 64;
    const int kb = ks * 2048;
    constexpr int NT = 32;

    // A: contiguous 8KB per k-tile; per-thread source pre-swizzled so the
    // LDS image (linear dest) matches the old swizzled layout exactly.
    const int srow = t >> 3, sc = t & 7;
    const uint16_t* asrc = S16T + (size_t)(mt * 4 + ks) * 131072
                           + srow * 64 + ((sc ^ (srow & 7)) << 3);
    const uint16_t* bsrc = ZTin + (size_t)srow * ZSTRIDE + kb
                           + ((sc ^ (srow & 7)) << 3);

    const int sw   = m & 7;
    const int aoff = (rt * 16 + m) * 128 + ((g ^ sw) << 4);
    const int bof  = 8192 + (ch * 64 + m) * 128 + ((g ^ sw) << 4);

    f32x4 acc[4] = {};

    auto stage = [&](int buf, int kt) {
        uint8_t* b = smem[buf];
        gl2lds16(asrc + kt * 4096, b + t * 16);
        gl2lds16(bsrc + kt * 64, b + 8192 + t * 16);
        gl2lds16(bsrc + (size_t)64 * ZSTRIDE + kt * 64, b + 16384 + t * 16);
    };

    stage(0, 0);
    stage(1, 1);
    int cur = 0;
#pragma unroll 1
    for (int kt = 0; kt < NT; ++kt) {
        if (kt + 2 < NT) {
            int nxt = cur + 2; if (nxt >= 3) nxt -= 3;
            stage(nxt, kt + 2);
            WAITV(6);                 // stage(kt) done; (kt+1),(kt+2) in flight
        } else if (kt + 2 == NT) {
            WAITV(3);
        } else {
            WAITV(0);
        }
        __builtin_amdgcn_s_barrier();
        __builtin_amdgcn_sched_barrier(0);
        const uint8_t* bb = smem[cur];
        bf16x8 a0 = ld16(bb + aoff);
        bf16x8 a1 = ld16(bb + (aoff ^ 64));
#pragma unroll
        for (int ct = 0; ct < 4; ++ct) {
            acc[ct] = __builtin_amdgcn_mfma_f32_16x16x32_bf16(
                a0, ld16(bb + bof + ct * 16 * 128), acc[ct], 0, 0, 0);
            acc[ct] = __builtin_amdgcn_mfma_f32_16x16x32_bf16(
                a1, ld16(bb + ((bof + ct * 16 * 128) ^ 64)), acc[ct], 0, 0, 0);
        }
        WAITL0;                       // my reads of buf landed
        __builtin_amdgcn_sched_barrier(0);
        __builtin_amdgcn_s_barrier(); // everyone done reading buf
        cur = (cur + 1 == 3) ? 0 : cur + 1;
    }

    float* pb = P + ((size_t)ks * NN + r0 + rt * 16 + 4 * g) * NF + ch * 64 + m;
#pragma unroll
    for (int ct = 0; ct < 4; ++ct)
#pragma unroll
        for (int i = 0; i < 4; ++i)
            pb[(size_t)i * NF + ct * 16] = acc[ct][i];
}

// ---- combine: Z = sum_ks P ; y += h*Z ; ZT' = bf16(Z^T) --------------------
template<bool WRITE_ZT>
__global__ __launch_bounds__(256) void k_combine(const float* __restrict__ P,
                                                 float* __restrict__ y,
                                                 uint16_t* __restrict__ ZTout,
                                                 const float* __restrict__ coeff,
                                                 int pass) {
    __shared__ float tile[16][NF + 4];
    const int t = threadIdx.x, r0 = blockIdx.x * 16;
    const float hk = coeff[pass];
    const int row = t >> 4, col = (t & 15) * 8;
    const size_t off = (size_t)(r0 + row) * NF + col;
    f32x4 s0 = *(const f32x4*)(P + off);
    f32x4 s1 = *(const f32x4*)(P + off + 4);
#pragma unroll
    for (int k = 1; k < 4; ++k) {
        s0 += *(const f32x4*)(P + (size_t)k * NN * NF + off);
        s1 += *(const f32x4*)(P + (size_t)k * NN * NF + off + 4);
    }
    float* yp = y + off;
    f32x4 y0 = *(const f32x4*)yp, y1 = *(const f32x4*)(yp + 4);
    *(f32x4*)yp       = y0 + hk * s0;
    *(f32x4*)(yp + 4) = y1 + hk * s1;
    if (WRITE_ZT) {
        *(f32x4*)&tile[row][col]     = s0;
        *(f32x4*)&tile[row][col + 4] = s1;
        __syncthreads();
        const int c = t >> 1, rh = t & 1;
        u16x8 pk;
#pragma unroll
        for (int e = 0; e < 8; ++e) pk[e] = f2bf(tile[rh * 8 + e][c]);
        *(u16x8*)(ZTout + (size_t)c * ZSTRIDE + r0 + rh * 8) = pk;
    }
}

extern "C" void kernel_launch(void* const* d_in, const int* in_sizes, int n_in,
                              void* d_out, int out_size, void* d_ws, size_t ws_size,
                              hipStream_t stream) {
    const float* X     = (const float*)d_in[0];
    const float* S     = (const float*)d_in[1];
    const float* coeff = (const float*)d_in[2];
    float* y = (float*)d_out;

    uint8_t* ws = (uint8_t*)d_ws;
    const size_t zb     = ((size_t)NF * ZSTRIDE * sizeof(uint16_t) + 255) & ~(size_t)255;
    const size_t s16b   = (size_t)NN * NN * sizeof(uint16_t);
    const size_t base   = 2 * zb + s16b;
    const size_t pslice = (size_t)NN * NF * sizeof(float);
    uint16_t* ZT0 = (uint16_t*)ws;
    uint16_t* ZT1 = (uint16_t*)(ws + zb);
    uint16_t* S16 = (uint16_t*)(ws + 2 * zb);
    float*    P   = (float*)(ws + base);

    // requires KS=4 workspace (every observed run has it)
    k_prep<<<dim3(512), dim3(256), 0, stream>>>(X, coeff, y, ZT0);
    k_convert_t<<<dim3(512), dim3(256), 0, stream>>>(S, S16);
    k_gemm_bf<<<dim3(512), dim3(512), 0, stream>>>(S16, ZT0, P);
    k_combine<true ><<<dim3(512), dim3(256), 0, stream>>>(P, y, ZT1, coeff, 1);
    k_gemm_bf<<<dim3(512), dim3(512), 0, stream>>>(S16, ZT1, P);
    k_combine<true ><<<dim3(512), dim3(256), 0, stream>>>(P, y, ZT0, coeff, 2);
    k_gemm_bf<<<dim3(512), dim3(512), 0, stream>>>(S16, ZT0, P);
    k_combine<false><<<dim3(512), dim3(256), 0, stream>>>(P, y, nullptr, coeff, 3);
}